// Round 6
// baseline (341.329 us; speedup 1.0000x reference)
//
#include <hip/hip_runtime.h>
#include <hip/hip_bf16.h>

#define NCLS 100
#define DIM  512
#define EPSV 1e-8f
#define NSPLIT 32        // blocks per class in segsum (32 -> ~31 rows/block, 3200 blocks)
#define IDXBUF 128       // LDS index staging per batch (rows/split ~31 << 128)
#define SCAT_ROWS 1024   // rows per scatter block

// ---------------- histogram + scan fused (last-done block scans) ----------------
__global__ __launch_bounds__(256) void hist_scan_kernel(const int* __restrict__ label,
                                                        int* __restrict__ cnt,
                                                        int* __restrict__ done,
                                                        int* __restrict__ base,
                                                        int* __restrict__ cursor, int n) {
    __shared__ int h[NCLS];
    const int tid = threadIdx.x;
    for (int i = tid; i < NCLS; i += 256) h[i] = 0;
    __syncthreads();
    for (int i = blockIdx.x * 256 + tid; i < n; i += gridDim.x * 256)
        atomicAdd(&h[label[i]], 1);
    __syncthreads();
    for (int i = tid; i < NCLS; i += 256) {
        int v = h[i];
        if (v) atomicAdd(&cnt[i], v);
    }
    __threadfence();
    __shared__ int last;
    if (tid == 0) last = (atomicAdd(done, 1) == (int)gridDim.x - 1);
    __syncthreads();
    if (!last) return;

    // last block: exclusive scan of cnt into base/cursor
    __shared__ int a[128];
    int myv = 0;
    if (tid < 128) {
        myv = (tid < NCLS) ? atomicAdd(&cnt[tid], 0) : 0;  // coherent read
        a[tid] = myv;
    }
    __syncthreads();
    #pragma unroll
    for (int off = 1; off < 128; off <<= 1) {
        int v = (tid < 128 && tid >= off) ? a[tid - off] : 0;
        __syncthreads();
        if (tid < 128) a[tid] += v;
        __syncthreads();
    }
    if (tid < NCLS) {
        const int excl = a[tid] - myv;
        base[tid] = excl;
        cursor[tid] = excl;
    }
}

// ---------------- counting-sort scatter: perm groups rows by class ----------------
__global__ __launch_bounds__(256) void scatter_kernel(const int* __restrict__ label,
                                                      int* __restrict__ cursor,
                                                      int* __restrict__ perm, int n) {
    __shared__ int h[NCLS];
    __shared__ int starts[NCLS];
    const int tid = threadIdx.x;
    for (int i = tid; i < NCLS; i += 256) h[i] = 0;
    __syncthreads();

    const int r0 = blockIdx.x * SCAT_ROWS;
    int c[4], lr[4];
    #pragma unroll
    for (int k = 0; k < 4; ++k) {
        const int r = r0 + k * 256 + tid;
        if (r < n) { c[k] = label[r]; lr[k] = atomicAdd(&h[c[k]], 1); }
        else c[k] = -1;
    }
    __syncthreads();
    for (int i = tid; i < NCLS; i += 256)
        starts[i] = h[i] ? atomicAdd(&cursor[i], h[i]) : 0;
    __syncthreads();
    #pragma unroll
    for (int k = 0; k < 4; ++k)
        if (c[k] >= 0) perm[starts[c[k]] + lr[k]] = r0 + k * 256 + tid;
}

// ---------------- segment sum over sorted rows ----------------
// grid = (NSPLIT, NCLS). Thread covers 4 dims (float4); 128 threads span a row,
// block processes 2 rows in parallel, unrolled 8x (16 rows/iter).
__global__ __launch_bounds__(256) void segsum_kernel(const float* __restrict__ feat,
                                                     const int* __restrict__ perm,
                                                     const int* __restrict__ base,
                                                     const int* __restrict__ cnt,
                                                     float* __restrict__ sums) {
    const int s = blockIdx.x;
    const int c = blockIdx.y;
    const int m = cnt[c];
    const int b = base[c];
    const int jlo = b + (m * s) / NSPLIT;
    const int jhi = b + (m * (s + 1)) / NSPLIT;

    __shared__ int idx[IDXBUF];
    const int tid  = threadIdx.x;
    const int half = tid >> 7;          // row parity
    const int dq   = (tid & 127) * 4;   // dim offset

    float4 acc = {0.0f, 0.0f, 0.0f, 0.0f};

    for (int j0 = jlo; j0 < jhi; j0 += IDXBUF) {
        const int batch = min(IDXBUF, jhi - j0);
        __syncthreads();
        for (int i = tid; i < batch; i += 256) idx[i] = perm[j0 + i];
        __syncthreads();
        int i = half;
        for (; i + 14 < batch; i += 16) {
            float4 v[8];
            #pragma unroll
            for (int u = 0; u < 8; ++u)
                v[u] = *(const float4*)(feat + (size_t)idx[i + 2 * u] * DIM + dq);
            #pragma unroll
            for (int u = 0; u < 8; ++u) {
                acc.x += v[u].x; acc.y += v[u].y; acc.z += v[u].z; acc.w += v[u].w;
            }
        }
        for (; i < batch; i += 2) {
            float4 v = *(const float4*)(feat + (size_t)idx[i] * DIM + dq);
            acc.x += v.x; acc.y += v.y; acc.z += v.z; acc.w += v.w;
        }
    }
    if (m > 0) {
        float* dst = &sums[(size_t)c * DIM + dq];
        atomicAdd(dst + 0, acc.x); atomicAdd(dst + 1, acc.y);
        atomicAdd(dst + 2, acc.z); atomicAdd(dst + 3, acc.w);
    }
}

// ---------------- normalized means: mhat = mean / max(||mean||, eps) ----------------
__global__ __launch_bounds__(256) void finalize_kernel(const float* __restrict__ sums,
                                                       const int* __restrict__ cnt,
                                                       float* __restrict__ mhat) {
    const int c = blockIdx.x;
    const float inv = 1.0f / fmaxf((float)cnt[c], 1.0f);
    const int t = threadIdx.x;
    float m0 = sums[(size_t)c * DIM + t] * inv;
    float m1 = sums[(size_t)c * DIM + 256 + t] * inv;
    float ss = m0 * m0 + m1 * m1;
    #pragma unroll
    for (int off = 32; off; off >>= 1) ss += __shfl_down(ss, off, 64);
    __shared__ float red[4];
    if ((t & 63) == 0) red[t >> 6] = ss;
    __syncthreads();
    const float tot = red[0] + red[1] + red[2] + red[3];
    const float q = 1.0f / fmaxf(sqrtf(tot), EPSV);
    mhat[(size_t)c * DIM + t] = m0 * q;
    mhat[(size_t)c * DIM + 256 + t] = m1 * q;
}

// ---------------- cosine: 16 lanes per row, 4 rows per wave ----------------
__global__ __launch_bounds__(256) void cos_kernel(const float* __restrict__ feat,
                                                  const int* __restrict__ label,
                                                  const float* __restrict__ mhat,
                                                  float* __restrict__ out, int n) {
    const int lane = threadIdx.x & 63;
    const int wv   = threadIdx.x >> 6;
    const int cl   = lane >> 4;
    const int t    = lane & 15;

    const int row = blockIdx.x * 16 + wv * 4 + cl;
    const bool ok = row < n;
    const int rr = ok ? row : (n - 1);

    const int c = label[rr];
    const float4* f4 = (const float4*)(feat + (size_t)rr * DIM);
    const float4* m4 = (const float4*)(mhat + (size_t)c  * DIM);

    float4 a[8], b[8];
    #pragma unroll
    for (int j = 0; j < 8; ++j) a[j] = f4[t + 16 * j];
    #pragma unroll
    for (int j = 0; j < 8; ++j) b[j] = m4[t + 16 * j];

    float dot = 0.0f, nf = 0.0f;
    #pragma unroll
    for (int j = 0; j < 8; ++j) {
        dot += a[j].x * b[j].x + a[j].y * b[j].y + a[j].z * b[j].z + a[j].w * b[j].w;
        nf  += a[j].x * a[j].x + a[j].y * a[j].y + a[j].z * a[j].z + a[j].w * a[j].w;
    }

    #pragma unroll
    for (int off = 8; off; off >>= 1) {
        dot += __shfl_xor(dot, off, 64);
        nf  += __shfl_xor(nf,  off, 64);
    }
    if (t == 0 && ok) {
        out[row] = dot / fmaxf(sqrtf(nf), EPSV);
    }
}

extern "C" void kernel_launch(void* const* d_in, const int* in_sizes, int n_in,
                              void* d_out, int out_size, void* d_ws, size_t ws_size,
                              hipStream_t stream) {
    const float* feat  = (const float*)d_in[0];
    const int*   label = (const int*)d_in[1];
    float*       out   = (float*)d_out;
    const int n = in_sizes[0] / DIM;   // 100000

    // ws layout (4 B units):
    // sums[100*512] | cnt[128] | done[128] | mhat[100*512] | base[128] | cursor[128] | perm[n]
    float* sums   = (float*)d_ws;
    int*   cnt    = (int*)(sums + NCLS * DIM);
    int*   done   = cnt + 128;
    float* mhat   = (float*)(done + 128);
    int*   base   = (int*)(mhat + NCLS * DIM);
    int*   cursor = base + 128;
    int*   perm   = cursor + 128;

    // zero sums + cnt + done (ws is poisoned 0xAA before every call)
    hipMemsetAsync(d_ws, 0, (NCLS * DIM + 256) * sizeof(float), stream);

    hist_scan_kernel<<<160, 256, 0, stream>>>(label, cnt, done, base, cursor, n);
    scatter_kernel<<<(n + SCAT_ROWS - 1) / SCAT_ROWS, 256, 0, stream>>>(label, cursor, perm, n);

    dim3 sg(NSPLIT, NCLS);             // 3200 blocks
    segsum_kernel<<<sg, 256, 0, stream>>>(feat, perm, base, cnt, sums);

    finalize_kernel<<<NCLS, 256, 0, stream>>>(sums, cnt, mhat);

    cos_kernel<<<(n + 15) / 16, 256, 0, stream>>>(feat, label, mhat, out, n);
}

// Round 7
// 332.985 us; speedup vs baseline: 1.0251x; 1.0251x over previous
//
#include <hip/hip_runtime.h>
#include <hip/hip_bf16.h>

#define NCLS 100
#define DIM  512
#define EPSV 1e-8f
#define NSPLIT 16        // blocks per class in segsum (R6 tried 32: -9us regression, reverted)
#define IDXBUF 512       // LDS index staging per batch
#define SCAT_ROWS 1024   // rows per scatter block

// ---------------- histogram of labels ----------------
// (R6 tried fusing the scan in via last-done-block + __threadfence: regression, reverted)
__global__ __launch_bounds__(256) void hist_kernel(const int* __restrict__ label,
                                                   int* __restrict__ cnt, int n) {
    __shared__ int h[NCLS];
    for (int i = threadIdx.x; i < NCLS; i += 256) h[i] = 0;
    __syncthreads();
    for (int i = blockIdx.x * 256 + threadIdx.x; i < n; i += gridDim.x * 256)
        atomicAdd(&h[label[i]], 1);
    __syncthreads();
    for (int i = threadIdx.x; i < NCLS; i += 256) {
        int v = h[i];
        if (v) atomicAdd(&cnt[i], v);
    }
}

// ---------------- parallel exclusive scan over 100 classes ----------------
__global__ __launch_bounds__(128) void scan_kernel(const int* __restrict__ cnt,
                                                   int* __restrict__ base,
                                                   int* __restrict__ cursor) {
    __shared__ int a[128];
    const int t = threadIdx.x;
    a[t] = (t < NCLS) ? cnt[t] : 0;
    __syncthreads();
    #pragma unroll
    for (int off = 1; off < 128; off <<= 1) {
        int v = (t >= off) ? a[t - off] : 0;
        __syncthreads();
        a[t] += v;
        __syncthreads();
    }
    if (t < NCLS) {
        int excl = a[t] - cnt[t];   // inclusive -> exclusive
        base[t] = excl;
        cursor[t] = excl;
    }
}

// ---------------- counting-sort scatter: perm groups rows by class ----------------
__global__ __launch_bounds__(256) void scatter_kernel(const int* __restrict__ label,
                                                      int* __restrict__ cursor,
                                                      int* __restrict__ perm, int n) {
    __shared__ int h[NCLS];
    __shared__ int starts[NCLS];
    const int tid = threadIdx.x;
    for (int i = tid; i < NCLS; i += 256) h[i] = 0;
    __syncthreads();

    const int r0 = blockIdx.x * SCAT_ROWS;
    int c[4], lr[4];
    #pragma unroll
    for (int k = 0; k < 4; ++k) {
        const int r = r0 + k * 256 + tid;
        if (r < n) { c[k] = label[r]; lr[k] = atomicAdd(&h[c[k]], 1); }
        else c[k] = -1;
    }
    __syncthreads();
    for (int i = tid; i < NCLS; i += 256)
        starts[i] = h[i] ? atomicAdd(&cursor[i], h[i]) : 0;
    __syncthreads();
    #pragma unroll
    for (int k = 0; k < 4; ++k)
        if (c[k] >= 0) perm[starts[c[k]] + lr[k]] = r0 + k * 256 + tid;
}

// ---------------- segment sum over sorted rows ----------------
// grid = (NSPLIT, NCLS). Thread covers 4 dims (float4); 128 threads span a row,
// the block processes 2 rows in parallel, unrolled 8x (16 rows/iter).
__global__ __launch_bounds__(256) void segsum_kernel(const float* __restrict__ feat,
                                                     const int* __restrict__ perm,
                                                     const int* __restrict__ base,
                                                     const int* __restrict__ cnt,
                                                     float* __restrict__ sums) {
    const int s = blockIdx.x;
    const int c = blockIdx.y;
    const int m = cnt[c];
    const int b = base[c];
    const int jlo = b + (m * s) / NSPLIT;
    const int jhi = b + (m * (s + 1)) / NSPLIT;

    __shared__ int idx[IDXBUF];
    const int tid  = threadIdx.x;
    const int half = tid >> 7;          // row parity
    const int dq   = (tid & 127) * 4;   // dim offset

    float4 acc = {0.0f, 0.0f, 0.0f, 0.0f};

    for (int j0 = jlo; j0 < jhi; j0 += IDXBUF) {
        const int batch = min(IDXBUF, jhi - j0);
        __syncthreads();
        for (int i = tid; i < batch; i += 256) idx[i] = perm[j0 + i];
        __syncthreads();
        int i = half;
        for (; i + 14 < batch; i += 16) {
            float4 v[8];
            #pragma unroll
            for (int u = 0; u < 8; ++u)
                v[u] = *(const float4*)(feat + (size_t)idx[i + 2 * u] * DIM + dq);
            #pragma unroll
            for (int u = 0; u < 8; ++u) {
                acc.x += v[u].x; acc.y += v[u].y; acc.z += v[u].z; acc.w += v[u].w;
            }
        }
        for (; i < batch; i += 2) {
            float4 v = *(const float4*)(feat + (size_t)idx[i] * DIM + dq);
            acc.x += v.x; acc.y += v.y; acc.z += v.z; acc.w += v.w;
        }
    }
    if (m > 0) {
        float* dst = &sums[(size_t)c * DIM + dq];
        atomicAdd(dst + 0, acc.x); atomicAdd(dst + 1, acc.y);
        atomicAdd(dst + 2, acc.z); atomicAdd(dst + 3, acc.w);
    }
}

// ---------------- normalized means: mhat = mean / max(||mean||, eps) ----------------
__global__ __launch_bounds__(256) void finalize_kernel(const float* __restrict__ sums,
                                                       const int* __restrict__ cnt,
                                                       float* __restrict__ mhat) {
    const int c = blockIdx.x;
    const float inv = 1.0f / fmaxf((float)cnt[c], 1.0f);
    const int t = threadIdx.x;
    float m0 = sums[(size_t)c * DIM + t] * inv;
    float m1 = sums[(size_t)c * DIM + 256 + t] * inv;
    float ss = m0 * m0 + m1 * m1;
    #pragma unroll
    for (int off = 32; off; off >>= 1) ss += __shfl_down(ss, off, 64);
    __shared__ float red[4];
    if ((t & 63) == 0) red[t >> 6] = ss;
    __syncthreads();
    const float tot = red[0] + red[1] + red[2] + red[3];
    const float q = 1.0f / fmaxf(sqrtf(tot), EPSV);
    mhat[(size_t)c * DIM + t] = m0 * q;
    mhat[(size_t)c * DIM + 256 + t] = m1 * q;
}

// ---------------- cosine: 16 lanes per row, 4 rows per wave ----------------
__global__ __launch_bounds__(256) void cos_kernel(const float* __restrict__ feat,
                                                  const int* __restrict__ label,
                                                  const float* __restrict__ mhat,
                                                  float* __restrict__ out, int n) {
    const int lane = threadIdx.x & 63;
    const int wv   = threadIdx.x >> 6;
    const int cl   = lane >> 4;
    const int t    = lane & 15;

    const int row = blockIdx.x * 16 + wv * 4 + cl;
    const bool ok = row < n;
    const int rr = ok ? row : (n - 1);

    const int c = label[rr];
    const float4* f4 = (const float4*)(feat + (size_t)rr * DIM);
    const float4* m4 = (const float4*)(mhat + (size_t)c  * DIM);

    float4 a[8], b[8];
    #pragma unroll
    for (int j = 0; j < 8; ++j) a[j] = f4[t + 16 * j];
    #pragma unroll
    for (int j = 0; j < 8; ++j) b[j] = m4[t + 16 * j];

    float dot = 0.0f, nf = 0.0f;
    #pragma unroll
    for (int j = 0; j < 8; ++j) {
        dot += a[j].x * b[j].x + a[j].y * b[j].y + a[j].z * b[j].z + a[j].w * b[j].w;
        nf  += a[j].x * a[j].x + a[j].y * a[j].y + a[j].z * a[j].z + a[j].w * a[j].w;
    }

    #pragma unroll
    for (int off = 8; off; off >>= 1) {
        dot += __shfl_xor(dot, off, 64);
        nf  += __shfl_xor(nf,  off, 64);
    }
    if (t == 0 && ok) {
        out[row] = dot / fmaxf(sqrtf(nf), EPSV);
    }
}

extern "C" void kernel_launch(void* const* d_in, const int* in_sizes, int n_in,
                              void* d_out, int out_size, void* d_ws, size_t ws_size,
                              hipStream_t stream) {
    const float* feat  = (const float*)d_in[0];
    const int*   label = (const int*)d_in[1];
    float*       out   = (float*)d_out;
    const int n = in_sizes[0] / DIM;   // 100000

    // ws layout (4 B units):
    // sums[100*512] | cnt[128] | mhat[100*512] | base[128] | cursor[128] | perm[n]
    float* sums   = (float*)d_ws;
    int*   cnt    = (int*)(sums + NCLS * DIM);
    float* mhat   = (float*)(cnt + 128);
    int*   base   = (int*)(mhat + NCLS * DIM);
    int*   cursor = base + 128;
    int*   perm   = cursor + 128;

    // zero sums + cnt (ws is poisoned 0xAA before every call)
    hipMemsetAsync(d_ws, 0, (NCLS * DIM + 128) * sizeof(float), stream);

    hist_kernel<<<160, 256, 0, stream>>>(label, cnt, n);
    scan_kernel<<<1, 128, 0, stream>>>(cnt, base, cursor);
    scatter_kernel<<<(n + SCAT_ROWS - 1) / SCAT_ROWS, 256, 0, stream>>>(label, cursor, perm, n);

    dim3 sg(NSPLIT, NCLS);             // 1600 blocks
    segsum_kernel<<<sg, 256, 0, stream>>>(feat, perm, base, cnt, sums);

    finalize_kernel<<<NCLS, 256, 0, stream>>>(sums, cnt, mhat);

    cos_kernel<<<(n + 15) / 16, 256, 0, stream>>>(feat, label, mhat, out, n);
}